// Round 7
// baseline (558.163 us; speedup 1.0000x reference)
//
#include <hip/hip_runtime.h>
#include <stdint.h>

#define T_TOK 8192   // B*S
#define HDIM  1024
#define FDIM  4096
#define NEXP  8
#define BT    256    // GEMM tile M=N
#define RCAP  (2*T_TOK + NEXP*256)   // 18432 padded rows
#define LDSB  65536  // bytes per LDS double-buffer half (A 32K + B 32K)

typedef short  short8  __attribute__((ext_vector_type(8)));
typedef unsigned short ushort8 __attribute__((ext_vector_type(8)));
typedef float  f32x16  __attribute__((ext_vector_type(16)));

#define MFMA32 __builtin_amdgcn_mfma_f32_32x32x16_bf16

__device__ __forceinline__ unsigned short f2bf(float f) {
  unsigned u = __float_as_uint(f);
  u += 0x7fffu + ((u >> 16) & 1u);   // RNE
  return (unsigned short)(u >> 16);
}
__device__ __forceinline__ float bf2f(unsigned short u) {
  return __uint_as_float((unsigned)u << 16);
}

__device__ __forceinline__ void gload16(const void* g, void* l) {
  __builtin_amdgcn_global_load_lds(
      (const __attribute__((address_space(1))) void*)g,
      (__attribute__((address_space(3))) void*)l, 16, 0, 0);
}

// Full 3-bit XOR swizzle: LDS rows are 128B (8 x 16B slots); slot ^= row&7.
// Writer (gload_lds, linear dst) compensates via pre-swizzled global source.
__device__ __forceinline__ const short8* lds_frag(const char* base, int row, int kbyte) {
  int b = row * 128 + (kbyte ^ ((row & 7) << 4));
  return (const short8*)(base + b);
}

// ---------------- weight transpose+convert: in [K][N] f32 -> out [N][K] bf16 ----------------
__global__ __launch_bounds__(256) void k_transp_cvt(const float* __restrict__ in,
                                                    unsigned short* __restrict__ out,
                                                    int K, int N) {
  __shared__ unsigned short s[64][72];
  const float* ine = in + (size_t)blockIdx.z * K * N;
  unsigned short* oute = out + (size_t)blockIdx.z * K * N;
  int k0 = blockIdx.y * 64, n0 = blockIdx.x * 64;
  int t = threadIdx.x;
  int kr = t >> 4, nc = (t & 15) * 4;
#pragma unroll
  for (int it = 0; it < 4; ++it) {
    int k = it * 16 + kr;
    float4 v = *(const float4*)(ine + (size_t)(k0 + k) * N + n0 + nc);
    ushort4 u = make_ushort4(f2bf(v.x), f2bf(v.y), f2bf(v.z), f2bf(v.w));
    *(ushort4*)(&s[k][nc]) = u;
  }
  __syncthreads();
  int nr = t >> 3, kc = (t & 7) * 8;
#pragma unroll
  for (int v = 0; v < 2; ++v) {
    int n = v * 32 + nr;
    ushort8 o;
#pragma unroll
    for (int j = 0; j < 8; ++j) o[j] = s[kc + j][n];
    *(ushort8*)(oute + (size_t)(n0 + n) * K + k0 + kc) = o;
  }
}

// ---------------- gating (+ fused x -> bf16 convert) ----------------
__global__ void k_gate(const float* __restrict__ x, const float* __restrict__ gw,
                       unsigned short* __restrict__ xb,
                       int2* __restrict__ eidx, float2* __restrict__ ewt) {
  int tid = threadIdx.x;
  int lane = tid & 63;
  int t = blockIdx.x * 4 + (tid >> 6);
  const float* xr = x + (size_t)t * HDIM;
  unsigned short* xbr = xb + (size_t)t * HDIM;
  float acc[NEXP];
#pragma unroll
  for (int e = 0; e < NEXP; e++) acc[e] = 0.f;
#pragma unroll
  for (int i = 0; i < HDIM / 64; i++) {
    float xv = xr[i * 64 + lane];
    xbr[i * 64 + lane] = f2bf(xv);
#pragma unroll
    for (int e = 0; e < NEXP; e++) acc[e] += xv * gw[e * HDIM + i * 64 + lane];
  }
#pragma unroll
  for (int e = 0; e < NEXP; e++) {
    acc[e] += __shfl_xor(acc[e], 32);
    acc[e] += __shfl_xor(acc[e], 16);
    acc[e] += __shfl_xor(acc[e], 8);
    acc[e] += __shfl_xor(acc[e], 4);
    acc[e] += __shfl_xor(acc[e], 2);
    acc[e] += __shfl_xor(acc[e], 1);
  }
  float m = acc[0];
#pragma unroll
  for (int e = 1; e < NEXP; e++) m = fmaxf(m, acc[e]);
  float p[NEXP]; float s = 0.f;
#pragma unroll
  for (int e = 0; e < NEXP; e++) { p[e] = expf(acc[e] - m); s += p[e]; }
  float inv = 1.f / s;
#pragma unroll
  for (int e = 0; e < NEXP; e++) p[e] *= inv;
  int b0 = 0; float v0 = p[0];
#pragma unroll
  for (int e = 1; e < NEXP; e++) if (p[e] > v0) { v0 = p[e]; b0 = e; }
  int b1i = (b0 == 0) ? 1 : 0; float v1 = p[b1i];
#pragma unroll
  for (int e = 0; e < NEXP; e++) if (e != b0 && p[e] > v1) { v1 = p[e]; b1i = e; }
  if (lane == 0) { eidx[t] = make_int2(b0, b1i); ewt[t] = make_float2(v0, v1); }
}

// ---------------- deterministic per-expert compaction ----------------
__global__ void k_compact(const int2* __restrict__ eidx,
                          int* __restrict__ list_tok, int* __restrict__ counts) {
  int e = blockIdx.x;
  int tid = threadIdx.x, lane = tid & 63, wid = tid >> 6;
  __shared__ int sbase;
  __shared__ int wcnt[4];
  if (tid == 0) sbase = 0;
  __syncthreads();
  for (int c = 0; c < T_TOK; c += 256) {
    int t = c + tid;
    int2 ei = eidx[t];
    bool sel = (ei.x == e) || (ei.y == e);
    unsigned long long b = __ballot(sel);
    if (lane == 0) wcnt[wid] = __popcll(b);
    __syncthreads();
    int pre = sbase;
    for (int w = 0; w < wid; w++) pre += wcnt[w];
    int pos = pre + __popcll(b & ((1ull << lane) - 1ull));
    if (sel) list_tok[e * T_TOK + pos] = t;
    __syncthreads();
    if (tid == 0) sbase += wcnt[0] + wcnt[1] + wcnt[2] + wcnt[3];
    __syncthreads();
  }
  if (tid == 0) counts[e] = sbase;
}

__global__ void k_offsets(const int* __restrict__ counts, int* __restrict__ off_pad) {
  if (threadIdx.x == 0) {
    int o = 0;
    off_pad[0] = 0;
    for (int e = 0; e < NEXP; e++) {
      o += ((counts[e] + BT - 1) / BT) * BT;
      off_pad[e + 1] = o;
    }
  }
}

// ---------------- invert token->padded-slot map (deterministic) ----------------
__global__ void k_invert(const int* __restrict__ list_tok, const int* __restrict__ counts,
                         const int* __restrict__ off_pad, const int2* __restrict__ eidx,
                         int2* __restrict__ tok2slot) {
  int e = blockIdx.y;
  int p = blockIdx.x * 256 + threadIdx.x;
  if (p < counts[e]) {
    int t = list_tok[e * T_TOK + p];
    int slot = off_pad[e] + p;
    if (eidx[t].x == e) tok2slot[t].x = slot;
    else                tok2slot[t].y = slot;
  }
}

// ======== shared GEMM machinery (macros reference kernel-local names) ========
// LDS map per buffer (v&1): A0 @0, A1 @16K, B0 @32K, B1 @48K. 16KB units of 128 rows x 128B.
#define STAGE_A(u_, v_) { \
    char* lb_ = smem + (((v_)&1) ? LDSB : 0) + (u_)*16384; \
    gload16(gA[u_][0] + (size_t)(v_)*128, lb_ + dst0); \
    gload16(gA[u_][1] + (size_t)(v_)*128, lb_ + dst1); }
#define STAGE_B(u_, v_) { \
    char* lb_ = smem + (((v_)&1) ? LDSB : 0) + 32768 + (u_)*16384; \
    gload16(gB[u_][0] + (size_t)(v_)*128, lb_ + dst0); \
    gload16(gB[u_][1] + (size_t)(v_)*128, lb_ + dst1); }

// One phase = half a K-tile (K=32, two ks-steps). 12 ds_read_b128 + 16 MFMA 32x32x16.
#define PHASE32(KS0, KS1, STAGE_STMT, TAIL_STMT) { \
    short8 a0_ = *lds_frag(rdA,      l31, (KS0)*32 + g16h); \
    short8 a1_ = *lds_frag(rdA, 32 + l31, (KS0)*32 + g16h); \
    short8 a2_ = *lds_frag(rdA, 64 + l31, (KS0)*32 + g16h); \
    short8 a3_ = *lds_frag(rdA, 96 + l31, (KS0)*32 + g16h); \
    short8 a4_ = *lds_frag(rdA,      l31, (KS1)*32 + g16h); \
    short8 a5_ = *lds_frag(rdA, 32 + l31, (KS1)*32 + g16h); \
    short8 a6_ = *lds_frag(rdA, 64 + l31, (KS1)*32 + g16h); \
    short8 a7_ = *lds_frag(rdA, 96 + l31, (KS1)*32 + g16h); \
    short8 b0_ = *lds_frag(rdB, rb +      l31, (KS0)*32 + g16h); \
    short8 b1_ = *lds_frag(rdB, rb + 32 + l31, (KS0)*32 + g16h); \
    short8 b2_ = *lds_frag(rdB, rb +      l31, (KS1)*32 + g16h); \
    short8 b3_ = *lds_frag(rdB, rb + 32 + l31, (KS1)*32 + g16h); \
    STAGE_STMT; \
    __builtin_amdgcn_s_barrier(); \
    asm volatile("s_waitcnt lgkmcnt(0)" ::: "memory"); \
    __builtin_amdgcn_sched_barrier(0); \
    __builtin_amdgcn_s_setprio(1); \
    acc[0][0] = MFMA32(a0_, b0_, acc[0][0], 0,0,0); \
    acc[1][0] = MFMA32(a1_, b0_, acc[1][0], 0,0,0); \
    acc[2][0] = MFMA32(a2_, b0_, acc[2][0], 0,0,0); \
    acc[3][0] = MFMA32(a3_, b0_, acc[3][0], 0,0,0); \
    acc[0][1] = MFMA32(a0_, b1_, acc[0][1], 0,0,0); \
    acc[1][1] = MFMA32(a1_, b1_, acc[1][1], 0,0,0); \
    acc[2][1] = MFMA32(a2_, b1_, acc[2][1], 0,0,0); \
    acc[3][1] = MFMA32(a3_, b1_, acc[3][1], 0,0,0); \
    acc[0][0] = MFMA32(a4_, b2_, acc[0][0], 0,0,0); \
    acc[1][0] = MFMA32(a5_, b2_, acc[1][0], 0,0,0); \
    acc[2][0] = MFMA32(a6_, b2_, acc[2][0], 0,0,0); \
    acc[3][0] = MFMA32(a7_, b2_, acc[3][0], 0,0,0); \
    acc[0][1] = MFMA32(a4_, b3_, acc[0][1], 0,0,0); \
    acc[1][1] = MFMA32(a5_, b3_, acc[1][1], 0,0,0); \
    acc[2][1] = MFMA32(a6_, b3_, acc[2][1], 0,0,0); \
    acc[3][1] = MFMA32(a7_, b3_, acc[3][1], 0,0,0); \
    __builtin_amdgcn_s_setprio(0); \
    TAIL_STMT; \
    __builtin_amdgcn_s_barrier(); }

#define GEMM_TILE_LOOP32(NT) \
  STAGE_A(0,0); STAGE_A(1,0); STAGE_B(0,0); STAGE_B(1,0); STAGE_B(0,1); STAGE_B(1,1); \
  asm volatile("s_waitcnt vmcnt(4)" ::: "memory"); \
  __builtin_amdgcn_s_barrier(); \
  for (int v = 0; v < (NT); ++v) { \
    const char* rdA = smem + ((v&1) ? LDSB : 0) + wm * 16384; \
    const char* rdB = smem + ((v&1) ? LDSB : 0) + 32768 + (wn >> 1) * 16384; \
    int rb = (wn & 1) * 64; \
    PHASE32(0, 1, { if (v+1 < (NT)) { STAGE_A(0, v+1); STAGE_A(1, v+1); } }, {}); \
    PHASE32(2, 3, {}, { \
      if (v+2 < (NT)) { STAGE_B(0, v+2); STAGE_B(1, v+2); \
                        asm volatile("s_waitcnt vmcnt(4)" ::: "memory"); } \
      else if (v+1 < (NT)) { asm volatile("s_waitcnt vmcnt(0)" ::: "memory"); } }); \
  }

// ---------------- GEMM1: h = silu(gather(x) @ w1[e] + b1[e]), 256x256 tile ----------------
__global__ __launch_bounds__(512, 2) void k_gemm1(
    const unsigned short* __restrict__ xb, const unsigned short* __restrict__ w1t,
    const float* __restrict__ b1, const int* __restrict__ list_tok,
    const int* __restrict__ counts, const int* __restrict__ off_pad,
    unsigned short* __restrict__ h) {
  extern __shared__ char smem[];
  // n-major XCD decode: XCD owns 2 n-columns, iterates all 72 m-blocks inner.
  int i2 = blockIdx.x >> 3;                       // 0..143
  int hi = (i2 >= 72) ? 1 : 0;
  int nIdx = ((blockIdx.x & 7) << 1) | hi;        // 0..15
  int mIdx = i2 - hi * 72;                        // 0..71
  int r0 = mIdx * BT;
  int n0 = nIdx * BT;
  if (r0 >= off_pad[NEXP]) return;
  int e = 0;
#pragma unroll
  for (int i = 0; i < NEXP; ++i) if (r0 >= off_pad[i + 1]) e = i + 1;
  int base = off_pad[e], cnt = counts[e];

  int t = threadIdx.x, l = t & 63, w = t >> 6;
  int wm = w >> 2, wn = w & 3;
  int l31 = l & 31, g16h = (l >> 5) * 16;

  int dst0 = t * 16, dst1 = t * 16 + 8192;
  int srow = t >> 3;
  int skb = (((t & 7) ^ ((t >> 3) & 7)) << 4);   // pre-swizzled source k-slot (matches lds_frag)
  const char* gA[2][2];
  const char* gB[2][2];
#pragma unroll
  for (int u = 0; u < 2; ++u)
#pragma unroll
    for (int j = 0; j < 2; ++j) {
      int row = u * 128 + srow + 64 * j;
      int se = r0 - base + row;
      int tok = (se < cnt) ? list_tok[e * T_TOK + se] : 0;
      gA[u][j] = (const char*)(xb + (size_t)tok * HDIM) + skb;
      gB[u][j] = (const char*)(w1t + (size_t)e * FDIM * HDIM + (size_t)(n0 + row) * HDIM) + skb;
    }

  f32x16 acc[4][2];
#pragma unroll
  for (int m = 0; m < 4; ++m)
#pragma unroll
    for (int n = 0; n < 2; ++n) acc[m][n] = (f32x16)(0.f);

  GEMM_TILE_LOOP32(HDIM / 64);

  // epilogue: bias+silu -> bf16 tile in LDS (bit5 col-XOR), coalesced 16B stores
  const float* b1e = b1 + (size_t)e * FDIM + n0;
  unsigned short* Cs = (unsigned short*)smem;
  int lhi = l >> 5;
#pragma unroll
  for (int nf = 0; nf < 2; ++nf) {
    int col = wn * 64 + nf * 32 + l31;
    int colX = col ^ (lhi << 5);
    float bv = b1e[col];
#pragma unroll
    for (int mf = 0; mf < 4; ++mf) {
      int rbase = wm * 128 + mf * 32 + 4 * lhi;
#pragma unroll
      for (int r = 0; r < 16; ++r) {
        int row = rbase + (r & 3) + 8 * (r >> 2);
        float vv = acc[mf][nf][r] + bv;
        float sg = __builtin_amdgcn_rcpf(1.f + __expf(-vv));
        Cs[(size_t)row * BT + colX] = f2bf(vv * sg);
      }
    }
  }
  __syncthreads();
#pragma unroll
  for (int s = 0; s < 16; ++s) {
    int lin = s * 512 + t;
    int row = lin >> 5, c8 = (lin & 31) * 8;
    int c8X = c8 ^ (((row >> 2) & 1) << 5);
    *(ushort8*)(h + (size_t)(r0 + row) * FDIM + n0 + c8) = *(const ushort8*)(Cs + (size_t)row * BT + c8X);
  }
}

// ---------------- GEMM2 (K-split 2): ypart{A,B}[slot][hcol] partials, no atomics ----------------
__global__ __launch_bounds__(512, 2) void k_gemm2(
    const unsigned short* __restrict__ h, const unsigned short* __restrict__ w2t,
    const float* __restrict__ b2, const int* __restrict__ off_pad,
    unsigned short* __restrict__ ypartA, unsigned short* __restrict__ ypartB) {
  extern __shared__ char smem[];
  // n-major XCD decode: XCD owns one (n,z) column, iterates all 72 m-blocks.
  int nz = blockIdx.x & 7;
  int mIdx = blockIdx.x >> 3;       // 0..71
  int r0 = mIdx * BT;               // slot block
  int n0 = (nz >> 1) * BT;          // hcol block
  int z  = nz & 1;                  // K half: f in [z*2048, z*2048+2048)
  if (r0 >= off_pad[NEXP]) return;
  int e = 0;
#pragma unroll
  for (int i = 0; i < NEXP; ++i) if (r0 >= off_pad[i + 1]) e = i + 1;

  int t = threadIdx.x, l = t & 63, w = t >> 6;
  int wm = w >> 2, wn = w & 3;
  int l31 = l & 31, g16h = (l >> 5) * 16;

  int dst0 = t * 16, dst1 = t * 16 + 8192;
  int srow = t >> 3;
  int skb = (((t & 7) ^ ((t >> 3) & 7)) << 4);
  const char* gA[2][2];
  const char* gB[2][2];
#pragma unroll
  for (int u = 0; u < 2; ++u)
#pragma unroll
    for (int j = 0; j < 2; ++j) {
      int row = u * 128 + srow + 64 * j;
      gA[u][j] = (const char*)(h + (size_t)(r0 + row) * FDIM + (size_t)z * 2048) + skb;
      gB[u][j] = (const char*)(w2t + (size_t)e * HDIM * FDIM + (size_t)(n0 + row) * FDIM + (size_t)z * 2048) + skb;
    }

  f32x16 acc[4][2];
#pragma unroll
  for (int m = 0; m < 4; ++m)
#pragma unroll
    for (int n = 0; n < 2; ++n) acc[m][n] = (f32x16)(0.f);

  GEMM_TILE_LOOP32(2048 / 64);

  // epilogue: (+b2 on z==0) -> bf16 tile in LDS (bit5 col-XOR), coalesced stores
  const float* b2e = b2 + (size_t)e * HDIM + n0;
  unsigned short* yp = z ? ypartB : ypartA;
  unsigned short* Cs = (unsigned short*)smem;
  int lhi = l >> 5;
#pragma unroll
  for (int nf = 0; nf < 2; ++nf) {
    int col = wn * 64 + nf * 32 + l31;
    int colX = col ^ (lhi << 5);
    float bv = (z == 0) ? b2e[col] : 0.f;
#pragma unroll
    for (int mf = 0; mf < 4; ++mf) {
      int rbase = wm * 128 + mf * 32 + 4 * lhi;
#pragma unroll
      for (int r = 0; r < 16; ++r) {
        int row = rbase + (r & 3) + 8 * (r >> 2);
        Cs[(size_t)row * BT + colX] = f2bf(acc[mf][nf][r] + bv);
      }
    }
  }
  __syncthreads();
#pragma unroll
  for (int s = 0; s < 16; ++s) {
    int lin = s * 512 + t;
    int row = lin >> 5, c8 = (lin & 31) * 8;
    int c8X = c8 ^ (((row >> 2) & 1) << 5);
    *(ushort8*)(yp + (size_t)(r0 + row) * HDIM + n0 + c8) = *(const ushort8*)(Cs + (size_t)row * BT + c8X);
  }
}

// ---------------- final combine: out[t] = w0*(yA+yB)[s0] + w1*(yA+yB)[s1] ----------------
__global__ void k_reduce(const unsigned short* __restrict__ ypartA,
                         const unsigned short* __restrict__ ypartB,
                         const int2* __restrict__ tok2slot, const float2* __restrict__ ewt,
                         float* __restrict__ out) {
  int idx = blockIdx.x * 256 + threadIdx.x;   // 8 cols per thread
  int t = idx >> 7;
  int c8 = (idx & 127) * 8;
  int2 s = tok2slot[t];
  float2 wv = ewt[t];
  ushort8 a0 = *(const ushort8*)(ypartA + (size_t)s.x * HDIM + c8);
  ushort8 a1 = *(const ushort8*)(ypartB + (size_t)s.x * HDIM + c8);
  ushort8 b0 = *(const ushort8*)(ypartA + (size_t)s.y * HDIM + c8);
  ushort8 b1 = *(const ushort8*)(ypartB + (size_t)s.y * HDIM + c8);
  float o[8];
#pragma unroll
  for (int j = 0; j < 8; ++j)
    o[j] = wv.x * (bf2f((unsigned short)a0[j]) + bf2f((unsigned short)a1[j]))
         + wv.y * (bf2f((unsigned short)b0[j]) + bf2f((unsigned short)b1[j]));
  float* op = out + (size_t)t * HDIM + c8;
  *(float4*)op = make_float4(o[0], o[1], o[2], o[3]);
  *(float4*)(op + 4) = make_float4(o[4], o[5], o[6], o[7]);
}

extern "C" void kernel_launch(void* const* d_in, const int* in_sizes, int n_in,
                              void* d_out, int out_size, void* d_ws, size_t ws_size,
                              hipStream_t stream) {
  const float* x  = (const float*)d_in[0];
  const float* gw = (const float*)d_in[1];
  const float* w1 = (const float*)d_in[2];
  const float* b1 = (const float*)d_in[3];
  const float* w2 = (const float*)d_in[4];
  const float* b2 = (const float*)d_in[5];
  float* out = (float*)d_out;

  char* ws = (char*)d_ws;
  size_t off = 0;
  unsigned short* xb = (unsigned short*)(ws + off); off += (size_t)T_TOK * HDIM * 2;
  int2*   eidx = (int2*)(ws + off);   off += (size_t)T_TOK * 8;
  float2* ewt  = (float2*)(ws + off); off += (size_t)T_TOK * 8;
  int2* tok2slot = (int2*)(ws + off); off += (size_t)T_TOK * 8;
  int*  list_tok = (int*)(ws + off);  off += (size_t)NEXP * T_TOK * 4;
  int* counts  = (int*)(ws + off); off += 64;
  int* off_pad = (int*)(ws + off); off += 64;
  off = (off + 255) & ~(size_t)255;
  unsigned short* h      = (unsigned short*)(ws + off); off += (size_t)RCAP * FDIM * 2;
  unsigned short* wT     = (unsigned short*)(ws + off); off += (size_t)NEXP * HDIM * FDIM * 2;
  unsigned short* ypartA = (unsigned short*)(ws + off); off += (size_t)RCAP * HDIM * 2;
  unsigned short* ypartB = (unsigned short*)(ws + off); off += (size_t)RCAP * HDIM * 2;
  if (ws_size < off) return;  // workspace too small -> fail loudly

  hipFuncSetAttribute((const void*)k_gemm1, hipFuncAttributeMaxDynamicSharedMemorySize, 131072);
  hipFuncSetAttribute((const void*)k_gemm2, hipFuncAttributeMaxDynamicSharedMemorySize, 131072);

  k_gate<<<T_TOK / 4, 256, 0, stream>>>(x, gw, xb, eidx, ewt);
  k_compact<<<NEXP, 256, 0, stream>>>(eidx, list_tok, counts);
  k_offsets<<<1, 64, 0, stream>>>(counts, off_pad);
  k_invert<<<dim3(T_TOK / 256, NEXP), 256, 0, stream>>>(list_tok, counts, off_pad, eidx, tok2slot);
  // w1 [E][H][F] f32 -> wT [E][F][H] bf16
  k_transp_cvt<<<dim3(FDIM / 64, HDIM / 64, NEXP), 256, 0, stream>>>(w1, wT, HDIM, FDIM);
  k_gemm1<<<8 * 144, 512, 131072, stream>>>(xb, wT, b1, list_tok, counts, off_pad, h);
  // w2 [E][F][H] f32 -> wT [E][H][F] bf16 (buffer reuse after GEMM1)
  k_transp_cvt<<<dim3(HDIM / 64, FDIM / 64, NEXP), 256, 0, stream>>>(w2, wT, FDIM, HDIM);
  k_gemm2<<<8 * 72, 512, 131072, stream>>>(h, wT, b2, off_pad, ypartA, ypartB);
  k_reduce<<<T_TOK * (HDIM / 8) / 256, 256, 0, stream>>>(ypartA, ypartB, tok2slot, ewt, out);
}

// Round 8
// 508.132 us; speedup vs baseline: 1.0985x; 1.0985x over previous
//
#include <hip/hip_runtime.h>
#include <stdint.h>

#define T_TOK 8192   // B*S
#define HDIM  1024
#define FDIM  4096
#define NEXP  8
#define BT    256    // GEMM tile M=N
#define RCAP  (2*T_TOK + NEXP*256)   // 18432 padded rows
#define LDSB  65536  // bytes per LDS double-buffer half (A 32K + B 32K)

typedef short  short8  __attribute__((ext_vector_type(8)));
typedef unsigned short ushort8 __attribute__((ext_vector_type(8)));
typedef float  f32x4   __attribute__((ext_vector_type(4)));

#define MFMA __builtin_amdgcn_mfma_f32_16x16x32_bf16

__device__ __forceinline__ unsigned short f2bf(float f) {
  unsigned u = __float_as_uint(f);
  u += 0x7fffu + ((u >> 16) & 1u);   // RNE
  return (unsigned short)(u >> 16);
}
__device__ __forceinline__ float bf2f(unsigned short u) {
  return __uint_as_float((unsigned)u << 16);
}

__device__ __forceinline__ void gload16(const void* g, void* l) {
  __builtin_amdgcn_global_load_lds(
      (const __attribute__((address_space(1))) void*)g,
      (__attribute__((address_space(3))) void*)l, 16, 0, 0);
}

// ---------------- weight transpose+convert: in [K][N] f32 -> out [N][K] bf16 ----------------
__global__ __launch_bounds__(256) void k_transp_cvt(const float* __restrict__ in,
                                                    unsigned short* __restrict__ out,
                                                    int K, int N) {
  __shared__ unsigned short s[64][72];
  const float* ine = in + (size_t)blockIdx.z * K * N;
  unsigned short* oute = out + (size_t)blockIdx.z * K * N;
  int k0 = blockIdx.y * 64, n0 = blockIdx.x * 64;
  int t = threadIdx.x;
  int kr = t >> 4, nc = (t & 15) * 4;
#pragma unroll
  for (int it = 0; it < 4; ++it) {
    int k = it * 16 + kr;
    float4 v = *(const float4*)(ine + (size_t)(k0 + k) * N + n0 + nc);
    ushort4 u = make_ushort4(f2bf(v.x), f2bf(v.y), f2bf(v.z), f2bf(v.w));
    *(ushort4*)(&s[k][nc]) = u;
  }
  __syncthreads();
  int nr = t >> 3, kc = (t & 7) * 8;
#pragma unroll
  for (int v = 0; v < 2; ++v) {
    int n = v * 32 + nr;
    ushort8 o;
#pragma unroll
    for (int j = 0; j < 8; ++j) o[j] = s[kc + j][n];
    *(ushort8*)(oute + (size_t)(n0 + n) * K + k0 + kc) = o;
  }
}

// ---------------- gating (+ fused x -> bf16 convert) ----------------
__global__ void k_gate(const float* __restrict__ x, const float* __restrict__ gw,
                       unsigned short* __restrict__ xb,
                       int2* __restrict__ eidx, float2* __restrict__ ewt) {
  int tid = threadIdx.x;
  int lane = tid & 63;
  int t = blockIdx.x * 4 + (tid >> 6);
  const float* xr = x + (size_t)t * HDIM;
  unsigned short* xbr = xb + (size_t)t * HDIM;
  float acc[NEXP];
#pragma unroll
  for (int e = 0; e < NEXP; e++) acc[e] = 0.f;
#pragma unroll
  for (int i = 0; i < HDIM / 64; i++) {
    float xv = xr[i * 64 + lane];
    xbr[i * 64 + lane] = f2bf(xv);
#pragma unroll
    for (int e = 0; e < NEXP; e++) acc[e] += xv * gw[e * HDIM + i * 64 + lane];
  }
#pragma unroll
  for (int e = 0; e < NEXP; e++) {
    acc[e] += __shfl_xor(acc[e], 32);
    acc[e] += __shfl_xor(acc[e], 16);
    acc[e] += __shfl_xor(acc[e], 8);
    acc[e] += __shfl_xor(acc[e], 4);
    acc[e] += __shfl_xor(acc[e], 2);
    acc[e] += __shfl_xor(acc[e], 1);
  }
  float m = acc[0];
#pragma unroll
  for (int e = 1; e < NEXP; e++) m = fmaxf(m, acc[e]);
  float p[NEXP]; float s = 0.f;
#pragma unroll
  for (int e = 0; e < NEXP; e++) { p[e] = expf(acc[e] - m); s += p[e]; }
  float inv = 1.f / s;
#pragma unroll
  for (int e = 0; e < NEXP; e++) p[e] *= inv;
  int b0 = 0; float v0 = p[0];
#pragma unroll
  for (int e = 1; e < NEXP; e++) if (p[e] > v0) { v0 = p[e]; b0 = e; }
  int b1i = (b0 == 0) ? 1 : 0; float v1 = p[b1i];
#pragma unroll
  for (int e = 0; e < NEXP; e++) if (e != b0 && p[e] > v1) { v1 = p[e]; b1i = e; }
  if (lane == 0) { eidx[t] = make_int2(b0, b1i); ewt[t] = make_float2(v0, v1); }
}

// ---------------- deterministic per-expert compaction ----------------
__global__ void k_compact(const int2* __restrict__ eidx,
                          int* __restrict__ list_tok, int* __restrict__ counts) {
  int e = blockIdx.x;
  int tid = threadIdx.x, lane = tid & 63, wid = tid >> 6;
  __shared__ int sbase;
  __shared__ int wcnt[4];
  if (tid == 0) sbase = 0;
  __syncthreads();
  for (int c = 0; c < T_TOK; c += 256) {
    int t = c + tid;
    int2 ei = eidx[t];
    bool sel = (ei.x == e) || (ei.y == e);
    unsigned long long b = __ballot(sel);
    if (lane == 0) wcnt[wid] = __popcll(b);
    __syncthreads();
    int pre = sbase;
    for (int w = 0; w < wid; w++) pre += wcnt[w];
    int pos = pre + __popcll(b & ((1ull << lane) - 1ull));
    if (sel) list_tok[e * T_TOK + pos] = t;
    __syncthreads();
    if (tid == 0) sbase += wcnt[0] + wcnt[1] + wcnt[2] + wcnt[3];
    __syncthreads();
  }
  if (tid == 0) counts[e] = sbase;
}

__global__ void k_offsets(const int* __restrict__ counts, int* __restrict__ off_pad) {
  if (threadIdx.x == 0) {
    int o = 0;
    off_pad[0] = 0;
    for (int e = 0; e < NEXP; e++) {
      o += ((counts[e] + BT - 1) / BT) * BT;
      off_pad[e + 1] = o;
    }
  }
}

// ---------------- invert token->padded-slot map (deterministic) ----------------
__global__ void k_invert(const int* __restrict__ list_tok, const int* __restrict__ counts,
                         const int* __restrict__ off_pad, const int2* __restrict__ eidx,
                         int2* __restrict__ tok2slot) {
  int e = blockIdx.y;
  int p = blockIdx.x * 256 + threadIdx.x;
  if (p < counts[e]) {
    int t = list_tok[e * T_TOK + p];
    int slot = off_pad[e] + p;
    if (eidx[t].x == e) tok2slot[t].x = slot;
    else                tok2slot[t].y = slot;
  }
}

// ======== shared GEMM machinery (macros reference kernel-local names) ========
// LDS map per buffer (v&1): A0 @0, A1 @16K, B0 @32K, B1 @48K. 16KB units of 128 rows x 128B.
// LDS read addresses are hoisted: per-lane base (aoff*/boff*) + compile-time imm (m*2048).
#define STAGE_A(u_, v_) { \
    char* lb_ = smem + (((v_)&1) ? LDSB : 0) + (u_)*16384; \
    gload16(gA[u_][0] + (size_t)(v_)*128, lb_ + dst0); \
    gload16(gA[u_][1] + (size_t)(v_)*128, lb_ + dst1); }
#define STAGE_B(u_, v_) { \
    char* lb_ = smem + (((v_)&1) ? LDSB : 0) + 32768 + (u_)*16384; \
    gload16(gB[u_][0] + (size_t)(v_)*128, lb_ + dst0); \
    gload16(gB[u_][1] + (size_t)(v_)*128, lb_ + dst1); }

#define PHASE(MA, MB, STAGE_STMT, TAIL_STMT) { \
    short8 aA0 = *(const short8*)(pA0 + (MA)*2048); \
    short8 aA1 = *(const short8*)(pA1 + (MA)*2048); \
    short8 aB0 = *(const short8*)(pA0 + (MB)*2048); \
    short8 aB1 = *(const short8*)(pA1 + (MB)*2048); \
    STAGE_STMT; \
    __builtin_amdgcn_s_barrier(); \
    asm volatile("s_waitcnt lgkmcnt(0)" ::: "memory"); \
    __builtin_amdgcn_sched_barrier(0); \
    __builtin_amdgcn_s_setprio(1); \
    acc[MA][0] = MFMA(aA0, b00, acc[MA][0], 0,0,0); acc[MA][0] = MFMA(aA1, b01, acc[MA][0], 0,0,0); \
    acc[MA][1] = MFMA(aA0, b10, acc[MA][1], 0,0,0); acc[MA][1] = MFMA(aA1, b11, acc[MA][1], 0,0,0); \
    acc[MA][2] = MFMA(aA0, b20, acc[MA][2], 0,0,0); acc[MA][2] = MFMA(aA1, b21, acc[MA][2], 0,0,0); \
    acc[MA][3] = MFMA(aA0, b30, acc[MA][3], 0,0,0); acc[MA][3] = MFMA(aA1, b31, acc[MA][3], 0,0,0); \
    acc[MB][0] = MFMA(aB0, b00, acc[MB][0], 0,0,0); acc[MB][0] = MFMA(aB1, b01, acc[MB][0], 0,0,0); \
    acc[MB][1] = MFMA(aB0, b10, acc[MB][1], 0,0,0); acc[MB][1] = MFMA(aB1, b11, acc[MB][1], 0,0,0); \
    acc[MB][2] = MFMA(aB0, b20, acc[MB][2], 0,0,0); acc[MB][2] = MFMA(aB1, b21, acc[MB][2], 0,0,0); \
    acc[MB][3] = MFMA(aB0, b30, acc[MB][3], 0,0,0); acc[MB][3] = MFMA(aB1, b31, acc[MB][3], 0,0,0); \
    __builtin_amdgcn_s_setprio(0); \
    TAIL_STMT; \
    __builtin_amdgcn_s_barrier(); }

#define READ_B4 \
    short8 b00 = *(const short8*)(pB0),        b01 = *(const short8*)(pB1); \
    short8 b10 = *(const short8*)(pB0 + 2048), b11 = *(const short8*)(pB1 + 2048); \
    short8 b20 = *(const short8*)(pB0 + 4096), b21 = *(const short8*)(pB1 + 4096); \
    short8 b30 = *(const short8*)(pB0 + 6144), b31 = *(const short8*)(pB1 + 6144);

#define GEMM_TILE_LOOP(NT) \
  STAGE_A(0,0); STAGE_A(1,0); STAGE_B(0,0); STAGE_B(1,0); STAGE_B(0,1); STAGE_B(1,1); \
  asm volatile("s_waitcnt vmcnt(4)" ::: "memory"); \
  __builtin_amdgcn_s_barrier(); \
  for (int v = 0; v < (NT); ++v) { \
    const char* bufb = smem + ((v&1) ? LDSB : 0); \
    const char* pA0 = bufb + wm * 16384 + aoff0; \
    const char* pA1 = bufb + wm * 16384 + aoff1; \
    const char* pB0 = bufb + 32768 + (wn >> 1) * 16384 + boff0; \
    const char* pB1 = bufb + 32768 + (wn >> 1) * 16384 + boff1; \
    READ_B4; \
    PHASE(0, 1, { if (v+1 < (NT)) STAGE_A(0, v+1); }, {}); \
    PHASE(2, 3, { if (v+1 < (NT)) STAGE_A(1, v+1); }, {}); \
    PHASE(4, 5, { if (v+2 < (NT)) STAGE_B(0, v+2); }, {}); \
    PHASE(6, 7, { if (v+2 < (NT)) STAGE_B(1, v+2); }, { \
      if (v+2 < (NT))      { asm volatile("s_waitcnt vmcnt(4)" ::: "memory"); } \
      else if (v+1 < (NT)) { asm volatile("s_waitcnt vmcnt(0)" ::: "memory"); } }); \
  }

// ---------------- GEMM1: h = silu(gather(x) @ w1[e] + b1[e]), 256x256 tile ----------------
__global__ __launch_bounds__(512, 2) void k_gemm1(
    const unsigned short* __restrict__ xb, const unsigned short* __restrict__ w1t,
    const float* __restrict__ b1, const int* __restrict__ list_tok,
    const int* __restrict__ counts, const int* __restrict__ off_pad,
    unsigned short* __restrict__ h) {
  extern __shared__ char smem[];
  // m-major-within-XCD decode: 1152 blocks = 8 xcd * 144; 16 n-blocks share each m-block.
  int wl = (blockIdx.x & 7) * 144 + (blockIdx.x >> 3);
  int r0 = (wl >> 4) * BT;
  int n0 = (wl & 15) * BT;
  if (r0 >= off_pad[NEXP]) return;
  int e = 0;
#pragma unroll
  for (int i = 0; i < NEXP; ++i) if (r0 >= off_pad[i + 1]) e = i + 1;
  int base = off_pad[e], cnt = counts[e];

  int t = threadIdx.x, l = t & 63, w = t >> 6;
  int wm = w >> 2, wn = w & 3;
  int lr = l & 15, g16 = (l >> 4) * 16;
  int swz = (lr & 7) << 4;
  int aoff0 = lr * 128 + (g16 ^ swz);
  int aoff1 = lr * 128 + ((64 + g16) ^ swz);
  int boff0 = (wn & 1) * 8192 + aoff0;
  int boff1 = (wn & 1) * 8192 + aoff1;

  int dst0 = t * 16, dst1 = t * 16 + 8192;
  int srow = t >> 3;
  int skb = (((t & 7) ^ ((t >> 3) & 7)) << 4);   // pre-swizzled source k-slot
  const char* gA[2][2];
  const char* gB[2][2];
#pragma unroll
  for (int u = 0; u < 2; ++u)
#pragma unroll
    for (int j = 0; j < 2; ++j) {
      int row = u * 128 + srow + 64 * j;
      int se = r0 - base + row;
      int tok = (se < cnt) ? list_tok[e * T_TOK + se] : 0;
      gA[u][j] = (const char*)(xb + (size_t)tok * HDIM) + skb;
      gB[u][j] = (const char*)(w1t + (size_t)e * FDIM * HDIM + (size_t)(n0 + row) * HDIM) + skb;
    }

  f32x4 acc[8][4];
#pragma unroll
  for (int m = 0; m < 8; ++m)
#pragma unroll
    for (int n = 0; n < 4; ++n) acc[m][n] = (f32x4){0.f, 0.f, 0.f, 0.f};

  GEMM_TILE_LOOP(HDIM / 64);

  // epilogue: bias+silu -> bf16 tile in LDS (col-XOR-swizzled), coalesced 16B stores
  const float* b1e = b1 + (size_t)e * FDIM + n0;
  unsigned short* Cs = (unsigned short*)smem;
  int lh = l >> 4, lh4 = lh * 4;
  int cswz = lh << 4;
#pragma unroll
  for (int n = 0; n < 4; ++n) {
    int col = wn * 64 + n * 16 + lr;
    int colX = col ^ cswz;
    float bv = b1e[col];
#pragma unroll
    for (int m = 0; m < 8; ++m) {
      int row = wm * 128 + m * 16 + lh4;
#pragma unroll
      for (int i = 0; i < 4; ++i) {
        float vv = acc[m][n][i] + bv;
        float sg = __builtin_amdgcn_rcpf(1.f + __expf(-vv));
        Cs[(size_t)(row + i) * BT + colX] = f2bf(vv * sg);
      }
    }
  }
  __syncthreads();
#pragma unroll
  for (int s = 0; s < 16; ++s) {
    int lin = s * 512 + t;
    int row = lin >> 5, c8 = (lin & 31) * 8;
    int c8X = c8 ^ (((row >> 2) & 3) << 4);
    *(ushort8*)(h + (size_t)(r0 + row) * FDIM + n0 + c8) = *(const ushort8*)(Cs + (size_t)row * BT + c8X);
  }
}

// ---------------- GEMM2 (K-split 2): ypart{A,B}[slot][hcol] partials, no atomics ----------------
__global__ __launch_bounds__(512, 2) void k_gemm2(
    const unsigned short* __restrict__ h, const unsigned short* __restrict__ w2t,
    const float* __restrict__ b2, const int* __restrict__ off_pad,
    unsigned short* __restrict__ ypartA, unsigned short* __restrict__ ypartB) {
  extern __shared__ char smem[];
  // m-major-within-XCD decode: 576 blocks = 8 xcd * 72; 8 (n,z) share each m-block.
  int wl = (blockIdx.x & 7) * 72 + (blockIdx.x >> 3);
  int mB = wl >> 3, rem = wl & 7;
  int r0 = mB * BT;                 // slot block
  int n0 = (rem >> 1) * BT;         // hcol block
  int z  = rem & 1;                 // K half: f in [z*2048, z*2048+2048)
  if (r0 >= off_pad[NEXP]) return;
  int e = 0;
#pragma unroll
  for (int i = 0; i < NEXP; ++i) if (r0 >= off_pad[i + 1]) e = i + 1;

  int t = threadIdx.x, l = t & 63, w = t >> 6;
  int wm = w >> 2, wn = w & 3;
  int lr = l & 15, g16 = (l >> 4) * 16;
  int swz = (lr & 7) << 4;
  int aoff0 = lr * 128 + (g16 ^ swz);
  int aoff1 = lr * 128 + ((64 + g16) ^ swz);
  int boff0 = (wn & 1) * 8192 + aoff0;
  int boff1 = (wn & 1) * 8192 + aoff1;

  int dst0 = t * 16, dst1 = t * 16 + 8192;
  int srow = t >> 3;
  int skb = (((t & 7) ^ ((t >> 3) & 7)) << 4);
  const char* gA[2][2];
  const char* gB[2][2];
#pragma unroll
  for (int u = 0; u < 2; ++u)
#pragma unroll
    for (int j = 0; j < 2; ++j) {
      int row = u * 128 + srow + 64 * j;
      gA[u][j] = (const char*)(h + (size_t)(r0 + row) * FDIM + (size_t)z * 2048) + skb;
      gB[u][j] = (const char*)(w2t + (size_t)e * HDIM * FDIM + (size_t)(n0 + row) * FDIM + (size_t)z * 2048) + skb;
    }

  f32x4 acc[8][4];
#pragma unroll
  for (int m = 0; m < 8; ++m)
#pragma unroll
    for (int n = 0; n < 4; ++n) acc[m][n] = (f32x4){0.f, 0.f, 0.f, 0.f};

  GEMM_TILE_LOOP(2048 / 64);

  // epilogue: (+b2 on z==0) -> bf16 tile in LDS (col-XOR-swizzled), coalesced stores
  const float* b2e = b2 + (size_t)e * HDIM + n0;
  unsigned short* yp = z ? ypartB : ypartA;
  unsigned short* Cs = (unsigned short*)smem;
  int lh = l >> 4, lh4 = lh * 4;
  int cswz = lh << 4;
#pragma unroll
  for (int n = 0; n < 4; ++n) {
    int col = wn * 64 + n * 16 + lr;
    int colX = col ^ cswz;
    float bv = (z == 0) ? b2e[col] : 0.f;
#pragma unroll
    for (int m = 0; m < 8; ++m) {
      int row = wm * 128 + m * 16 + lh4;
#pragma unroll
      for (int i = 0; i < 4; ++i)
        Cs[(size_t)(row + i) * BT + colX] = f2bf(acc[m][n][i] + bv);
    }
  }
  __syncthreads();
#pragma unroll
  for (int s = 0; s < 16; ++s) {
    int lin = s * 512 + t;
    int row = lin >> 5, c8 = (lin & 31) * 8;
    int c8X = c8 ^ (((row >> 2) & 3) << 4);
    *(ushort8*)(yp + (size_t)(r0 + row) * HDIM + n0 + c8) = *(const ushort8*)(Cs + (size_t)row * BT + c8X);
  }
}

// ---------------- final combine: out[t] = w0*(yA+yB)[s0] + w1*(yA+yB)[s1] ----------------
__global__ void k_reduce(const unsigned short* __restrict__ ypartA,
                         const unsigned short* __restrict__ ypartB,
                         const int2* __restrict__ tok2slot, const float2* __restrict__ ewt,
                         float* __restrict__ out) {
  int idx = blockIdx.x * 256 + threadIdx.x;   // 8 cols per thread
  int t = idx >> 7;
  int c8 = (idx & 127) * 8;
  int2 s = tok2slot[t];
  float2 wv = ewt[t];
  ushort8 a0 = *(const ushort8*)(ypartA + (size_t)s.x * HDIM + c8);
  ushort8 a1 = *(const ushort8*)(ypartB + (size_t)s.x * HDIM + c8);
  ushort8 b0 = *(const ushort8*)(ypartA + (size_t)s.y * HDIM + c8);
  ushort8 b1 = *(const ushort8*)(ypartB + (size_t)s.y * HDIM + c8);
  float o[8];
#pragma unroll
  for (int j = 0; j < 8; ++j)
    o[j] = wv.x * (bf2f((unsigned short)a0[j]) + bf2f((unsigned short)a1[j]))
         + wv.y * (bf2f((unsigned short)b0[j]) + bf2f((unsigned short)b1[j]));
  float* op = out + (size_t)t * HDIM + c8;
  *(float4*)op = make_float4(o[0], o[1], o[2], o[3]);
  *(float4*)(op + 4) = make_float4(o[4], o[5], o[6], o[7]);
}

extern "C" void kernel_launch(void* const* d_in, const int* in_sizes, int n_in,
                              void* d_out, int out_size, void* d_ws, size_t ws_size,
                              hipStream_t stream) {
  const float* x  = (const float*)d_in[0];
  const float* gw = (const float*)d_in[1];
  const float* w1 = (const float*)d_in[2];
  const float* b1 = (const float*)d_in[3];
  const float* w2 = (const float*)d_in[4];
  const float* b2 = (const float*)d_in[5];
  float* out = (float*)d_out;

  char* ws = (char*)d_ws;
  size_t off = 0;
  unsigned short* xb = (unsigned short*)(ws + off); off += (size_t)T_TOK * HDIM * 2;
  int2*   eidx = (int2*)(ws + off);   off += (size_t)T_TOK * 8;
  float2* ewt  = (float2*)(ws + off); off += (size_t)T_TOK * 8;
  int2* tok2slot = (int2*)(ws + off); off += (size_t)T_TOK * 8;
  int*  list_tok = (int*)(ws + off);  off += (size_t)NEXP * T_TOK * 4;
  int* counts  = (int*)(ws + off); off += 64;
  int* off_pad = (int*)(ws + off); off += 64;
  off = (off + 255) & ~(size_t)255;
  unsigned short* h      = (unsigned short*)(ws + off); off += (size_t)RCAP * FDIM * 2;
  unsigned short* wT     = (unsigned short*)(ws + off); off += (size_t)NEXP * HDIM * FDIM * 2;
  unsigned short* ypartA = (unsigned short*)(ws + off); off += (size_t)RCAP * HDIM * 2;
  unsigned short* ypartB = (unsigned short*)(ws + off); off += (size_t)RCAP * HDIM * 2;
  if (ws_size < off) return;  // workspace too small -> fail loudly

  hipFuncSetAttribute((const void*)k_gemm1, hipFuncAttributeMaxDynamicSharedMemorySize, 131072);
  hipFuncSetAttribute((const void*)k_gemm2, hipFuncAttributeMaxDynamicSharedMemorySize, 131072);

  k_gate<<<T_TOK / 4, 256, 0, stream>>>(x, gw, xb, eidx, ewt);
  k_compact<<<NEXP, 256, 0, stream>>>(eidx, list_tok, counts);
  k_offsets<<<1, 64, 0, stream>>>(counts, off_pad);
  k_invert<<<dim3(T_TOK / 256, NEXP), 256, 0, stream>>>(list_tok, counts, off_pad, eidx, tok2slot);
  // w1 [E][H][F] f32 -> wT [E][F][H] bf16
  k_transp_cvt<<<dim3(FDIM / 64, HDIM / 64, NEXP), 256, 0, stream>>>(w1, wT, HDIM, FDIM);
  k_gemm1<<<8 * 144, 512, 131072, stream>>>(xb, wT, b1, list_tok, counts, off_pad, h);
  // w2 [E][F][H] f32 -> wT [E][H][F] bf16 (buffer reuse after GEMM1)
  k_transp_cvt<<<dim3(HDIM / 64, FDIM / 64, NEXP), 256, 0, stream>>>(w2, wT, FDIM, HDIM);
  k_gemm2<<<8 * 72, 512, 131072, stream>>>(h, wT, b2, off_pad, ypartA, ypartB);
  k_reduce<<<T_TOK * (HDIM / 8) / 256, 256, 0, stream>>>(ypartA, ypartB, tok2slot, ewt, out);
}